// Round 6
// baseline (437.701 us; speedup 1.0000x reference)
//
#include <hip/hip_runtime.h>
#include <hip/hip_cooperative_groups.h>

namespace cg = cooperative_groups;

#define NB 4
#define NC 32
#define NH 32
#define NW 32
#define KK 288                   // 32*3*3 patch length
#define PLANE (NB*NC*NH*NW)      // 131072 elements per plane
#define CHALF 16                 // channels per conv block (half split)

__device__ __forceinline__ float s3(float v) { return sqrtf(sqrtf(sqrtf(v))); }

// ---------- shared device helpers (used by fused + fallback paths) ----------

// Zero-mean one 288-long weight row; write padded float4 layout
// [co][c][r] = {w(r,0), w(r,1), w(r,2), pad}. 256 threads per row.
__device__ __forceinline__ void prep_row(const float* __restrict__ src,
                                         float* __restrict__ dst,
                                         int co, int tid, float* red)
{
    const float a = src[co*KK + tid];                              // tid < 256 < 288
    const float b = (tid + 256 < KK) ? src[co*KK + tid + 256] : 0.0f;
    red[tid] = a + b;
    __syncthreads();
    for (int s = 128; s > 0; s >>= 1) {
        if (tid < s) red[tid] += red[tid + s];
        __syncthreads();
    }
    const float mean = red[0] * (1.0f / (float)KK);
    {
        const int e = tid, c = e / 9, r9 = e - c*9, r = r9 / 3, kw = r9 - r*3;
        dst[co*384 + ((c*3 + r) << 2) + kw] = a - mean;
    }
    if (tid + 256 < KK) {
        const int e = tid + 256, c = e / 9, r9 = e - c*9, r = r9 / 3, kw = r9 - r*3;
        dst[co*384 + ((c*3 + r) << 2) + kw] = b - mean;
    }
}

// Half-channel norm-dist conv phase. One (h, cog, chalf, b) per block.
// STAGE1 stages x/l/u; STAGE2 stages s3(sum of conv1's two partials).
// Writes partial (pre-root) sums at [chalf*PLANE + o].
template<bool STAGE2>
__device__ __forceinline__ void conv_phase(
    int h, int cog, int chalf, int b, int tx, int ty, int tid,
    const float* __restrict__ sy, const float* __restrict__ sl,
    const float* __restrict__ su, const float* __restrict__ wf,
    float* __restrict__ pY, float* __restrict__ pL, float* __restrict__ pU,
    float4* __restrict__ sP)
{
    const int ch0 = chalf * CHALF;
    for (int i = tid; i < CHALF*3*34; i += 256) {
        const int c   = i / 102;
        const int rem = i - c*102;
        const int r   = rem / 34;
        const int col = rem - r*34;
        const int gh  = h + r - 1;
        const int gw  = col - 1;
        float vx = 0.0f, vl = 0.0f, vu = 0.0f;
        if ((unsigned)gh < NH && (unsigned)gw < NW) {
            const int g = ((b*NC + ch0 + c)*NH + gh)*NW + gw;
            if (STAGE2) {   // combine conv1 halves + eighth-root (relu no-op: >= 0)
                vx = s3(sy[g] + sy[PLANE + g]);
                vl = s3(sl[g] + sl[PLANE + g]);
                vu = s3(su[g] + su[PLANE + g]);
            } else {
                vx = sy[g]; vl = sl[g]; vu = su[g];
            }
        }
        sP[i] = make_float4(vx, vl, vu, 0.0f);
    }
    __syncthreads();

    const int co = cog*8 + ty;
    const float4* wb = (const float4*)wf + (co*NC + ch0)*3;

    float aY = 0.0f, aL = 0.0f, aU = 0.0f;
    auto tap = [&](float wv, float4 p) {
        const float d  = p.x - wv;              // y: |d|^8 = ((d^2)^2)^2
        const float d2 = d*d, d4 = d2*d2;
        aY = fmaf(d4, d4, aY);
        const float a  = p.y - wv;              // dl: max(a, nb, 0)^8 -> v_max3
        const float nb = wv - p.z;
        const float m  = fmaxf(fmaxf(a, nb), 0.0f);
        const float m2 = m*m, m4 = m2*m2;
        aL = fmaf(m4, m4, aL);
        const float mm  = fmaxf(fabsf(a), fabsf(nb));   // du: max(|a|,|nb|)^8
        const float mm2 = mm*mm, mm4 = mm2*mm2;
        aU = fmaf(mm4, mm4, aU);
    };

    #pragma unroll 2
    for (int c = 0; c < CHALF; ++c) {
        const float4 w0 = wb[c*3 + 0];
        const float4 w1 = wb[c*3 + 1];
        const float4 w2 = wb[c*3 + 2];
        const int pb = c*102 + tx;
        tap(w0.x, sP[pb +  0]); tap(w0.y, sP[pb +  1]); tap(w0.z, sP[pb +  2]);
        tap(w1.x, sP[pb + 34]); tap(w1.y, sP[pb + 35]); tap(w1.z, sP[pb + 36]);
        tap(w2.x, sP[pb + 68]); tap(w2.y, sP[pb + 69]); tap(w2.z, sP[pb + 70]);
    }

    const int o = ((b*NC + co)*NH + h)*NW + tx;
    pY[chalf*PLANE + o] = aY;
    pL[chalf*PLANE + o] = aL;
    pU[chalf*PLANE + o] = aU;
}

// ---------- fused cooperative kernel: prep | conv1 | conv2 | epilogue ----------
__global__ __launch_bounds__(256, 4) void fused_k(
    const float* __restrict__ x,  const float* __restrict__ l,  const float* __restrict__ u,
    const float* __restrict__ w1, const float* __restrict__ w2,
    float* __restrict__ wf1, float* __restrict__ wf2,
    float* __restrict__ p1Y, float* __restrict__ p1L, float* __restrict__ p1U,
    float* __restrict__ p2Y, float* __restrict__ p2L, float* __restrict__ p2U,
    float* __restrict__ out)
{
    __shared__ float4 sP[CHALF*3*34];   // 26112 B
    __shared__ float  red[256];         // prep scratch

    const int n  = blockIdx.x;          // 0..1023
    const int tx = threadIdx.x, ty = threadIdx.y, tid = ty*32 + tx;
    const int h = n & 31, yy = (n >> 5) & 7, b = n >> 8;
    const int cog = yy >> 1, chalf = yy & 1;

    if (n < 64)                          // phase A: weight prep (blocks 0..63)
        prep_row((n < 32) ? w1 : w2, (n < 32) ? wf1 : wf2, n & 31, tid, red);
    cg::this_grid().sync();

    conv_phase<false>(h, cog, chalf, b, tx, ty, tid, x, l, u, wf1, p1Y, p1L, p1U, sP);
    cg::this_grid().sync();

    conv_phase<true >(h, cog, chalf, b, tx, ty, tid, p1Y, p1L, p1U, wf2, p2Y, p2L, p2U, sP);
    cg::this_grid().sync();

    {                                    // phase D: combine + residual + relu
        const int o = n*256 + tid;
        if (o < PLANE) {
            const float y  = s3(p2Y[o] + p2Y[PLANE + o]);
            const float dl = s3(p2L[o] + p2L[PLANE + o]);
            const float du = s3(p2U[o] + p2U[PLANE + o]);
            out[o]           = fmaxf(y  + x[o], 0.0f);
            out[PLANE + o]   = fmaxf(dl + l[o], 0.0f);
            out[2*PLANE + o] = fmaxf(du + u[o], 0.0f);
        }
    }
}

// ---------- fallback path (if cooperative launch unsupported) ----------
__global__ __launch_bounds__(256) void prep_k(
    const float* __restrict__ w1, const float* __restrict__ w2,
    float* __restrict__ wf1, float* __restrict__ wf2)
{
    __shared__ float red[256];
    const int row = blockIdx.x;          // 0..63
    prep_row((row < 32) ? w1 : w2, (row < 32) ? wf1 : wf2, row & 31, threadIdx.x, red);
}

template<bool STAGE2>
__global__ __launch_bounds__(256, 4) void conv_k(
    const float* __restrict__ sy, const float* __restrict__ sl,
    const float* __restrict__ su, const float* __restrict__ wf,
    float* __restrict__ pY, float* __restrict__ pL, float* __restrict__ pU)
{
    __shared__ float4 sP[CHALF*3*34];
    const int h = blockIdx.x, yy = blockIdx.y, b = blockIdx.z;
    conv_phase<STAGE2>(h, yy >> 1, yy & 1, b, threadIdx.x, threadIdx.y,
                       threadIdx.y*32 + threadIdx.x, sy, sl, su, wf, pY, pL, pU, sP);
}

__global__ __launch_bounds__(256) void epi_k(
    const float* __restrict__ pY, const float* __restrict__ pL, const float* __restrict__ pU,
    const float* __restrict__ x,  const float* __restrict__ l,  const float* __restrict__ u,
    float* __restrict__ out)
{
    const int o = blockIdx.x*256 + threadIdx.x;
    const float y  = s3(pY[o] + pY[PLANE + o]);
    const float dl = s3(pL[o] + pL[PLANE + o]);
    const float du = s3(pU[o] + pU[PLANE + o]);
    out[o]           = fmaxf(y  + x[o], 0.0f);
    out[PLANE + o]   = fmaxf(dl + l[o], 0.0f);
    out[2*PLANE + o] = fmaxf(du + u[o], 0.0f);
}

extern "C" void kernel_launch(void* const* d_in, const int* in_sizes, int n_in,
                              void* d_out, int out_size, void* d_ws, size_t ws_size,
                              hipStream_t stream)
{
    const float* x  = (const float*)d_in[0];
    const float* l  = (const float*)d_in[1];
    const float* u  = (const float*)d_in[2];
    const float* w1 = (const float*)d_in[3];
    const float* w2 = (const float*)d_in[4];
    float* ws  = (float*)d_ws;
    float* wf1 = ws;                        // 12288 floats each (padded float4 layout)
    float* wf2 = wf1 + 12288;
    float* p1Y = wf2 + 12288;               // conv partials: [2][PLANE] each
    float* p1L = p1Y + 2*PLANE;
    float* p1U = p1L + 2*PLANE;
    float* p2Y = p1U + 2*PLANE;
    float* p2L = p2Y + 2*PLANE;
    float* p2U = p2L + 2*PLANE;
    float* out = (float*)d_out;

    void* args[14] = { (void*)&x, (void*)&l, (void*)&u, (void*)&w1, (void*)&w2,
                       (void*)&wf1, (void*)&wf2,
                       (void*)&p1Y, (void*)&p1L, (void*)&p1U,
                       (void*)&p2Y, (void*)&p2L, (void*)&p2U, (void*)&out };
    hipError_t err = hipLaunchCooperativeKernel((const void*)fused_k,
                                                dim3(1024), dim3(32, 8),
                                                args, 0, stream);
    if (err != hipSuccess) {
        (void)hipGetLastError();            // clear; use 4-dispatch fallback
        prep_k<<<64, 256, 0, stream>>>(w1, w2, wf1, wf2);
        dim3 blk(32, 8);
        dim3 grd(NH, 8, NB);
        conv_k<false><<<grd, blk, 0, stream>>>(x, l, u, wf1, p1Y, p1L, p1U);
        conv_k<true ><<<grd, blk, 0, stream>>>(p1Y, p1L, p1U, wf2, p2Y, p2L, p2U);
        epi_k<<<PLANE/256, 256, 0, stream>>>(p2Y, p2L, p2U, x, l, u, out);
    }
}

// Round 7
// 111.718 us; speedup vs baseline: 3.9179x; 3.9179x over previous
//
#include <hip/hip_runtime.h>

#define NB 4
#define NC 32
#define NH 32
#define NW 32
#define KK 288                   // 32*3*3 patch length
#define PLANE (NB*NC*NH*NW)      // 131072 elements per plane
#define CHALF 16                 // channels per conv1 block (half split)

__device__ __forceinline__ float s3(float v) { return sqrtf(sqrtf(sqrtf(v))); }

// In-block weight prep: load this cog's 8 rows of raw [32][288] weights,
// zero-mean each row, store padded float4 LDS layout [co<8][c<32][r<3] =
// {w(r,0), w(r,1), w(r,2), pad}. Requires __syncthreads() after (caller).
__device__ __forceinline__ void prep_weights_lds(
        const float* __restrict__ wraw, int cog, int tid, float* __restrict__ sWf)
{
    // stage raw into padded layout
    for (int i = tid; i < 8*KK; i += 256) {
        const int co  = i / KK;
        const int rem = i - co*KK;
        const int c   = rem / 9;
        const int r9  = rem - c*9;
        const int r   = r9 / 3;
        const int kw  = r9 - r*3;
        sWf[((co*NC + c)*3 + r)*4 + kw] = wraw[(cog*8 + co)*KK + rem];
    }
    __syncthreads();
    // zero-mean: thread (co = tid>>5, c = tid&31) owns 9 taps; width-32 reduce
    {
        float4* sW4 = (float4*)sWf;
        const int co = tid >> 5;
        const int c  = tid & 31;
        float4 a0 = sW4[(co*NC + c)*3 + 0];
        float4 a1 = sW4[(co*NC + c)*3 + 1];
        float4 a2 = sW4[(co*NC + c)*3 + 2];
        float s = a0.x+a0.y+a0.z + a1.x+a1.y+a1.z + a2.x+a2.y+a2.z;
        #pragma unroll
        for (int off = 16; off > 0; off >>= 1) s += __shfl_xor(s, off, 32);
        const float mean = s * (1.0f / (float)KK);
        a0.x -= mean; a0.y -= mean; a0.z -= mean; a0.w = 0.0f;
        a1.x -= mean; a1.y -= mean; a1.z -= mean; a1.w = 0.0f;
        a2.x -= mean; a2.y -= mean; a2.z -= mean; a2.w = 0.0f;
        sW4[(co*NC + c)*3 + 0] = a0;
        sW4[(co*NC + c)*3 + 1] = a1;
        sW4[(co*NC + c)*3 + 2] = a2;
    }
}

// 14-VALU tap: y(sub,2mul,fma) + dl-sub(a) + du-sub(nb) + dl(max3,2mul,fma) + du(max|.|,2mul,fma)
__device__ __forceinline__ void tap(float wv, float4 p, float& aY, float& aL, float& aU)
{
    const float d  = p.x - wv;
    const float d2 = d*d, d4 = d2*d2;
    aY = fmaf(d4, d4, aY);
    const float a  = p.y - wv;
    const float nb = wv - p.z;
    const float m  = fmaxf(fmaxf(a, nb), 0.0f);      // v_max3_f32
    const float m2 = m*m, m4 = m2*m2;
    aL = fmaf(m4, m4, aL);
    const float mm  = fmaxf(fabsf(a), fabsf(nb));    // v_max_f32 with abs mods
    const float mm2 = mm*mm, mm4 = mm2*mm2;
    aU = fmaf(mm4, mm4, aU);
}

// ---- dispatch 1: conv1, half-channel split ---------------------------------
// Block 32(w) x 8(co). Grid (h=32, cog*2+chalf=8, b=4) = 1024 blocks.
// Writes pre-root partial sums at [chalf*PLANE + o].
__global__ __launch_bounds__(256, 4) void conv1_k(
    const float* __restrict__ x,  const float* __restrict__ l,  const float* __restrict__ u,
    const float* __restrict__ w1,
    float* __restrict__ pY, float* __restrict__ pL, float* __restrict__ pU)
{
    const int h     = blockIdx.x;
    const int cog   = blockIdx.y >> 1;
    const int chalf = blockIdx.y & 1;
    const int ch0   = chalf * CHALF;
    const int b     = blockIdx.z;
    const int tx    = threadIdx.x;
    const int ty    = threadIdx.y;
    const int tid   = ty*32 + tx;

    __shared__ float4 sP[CHALF*3*34];        // 26112 B
    __shared__ float  sWf[8*NC*3*4];         // 12288 B (full 32-ch rows; mean needs all)

    prep_weights_lds(w1, cog, tid, sWf);     // syncthreads below covers both

    for (int i = tid; i < CHALF*3*34; i += 256) {
        const int c   = i / 102;
        const int rem = i - c*102;
        const int r   = rem / 34;
        const int col = rem - r*34;
        const int gh  = h + r - 1;
        const int gw  = col - 1;
        float vx = 0.0f, vl = 0.0f, vu = 0.0f;
        if ((unsigned)gh < NH && (unsigned)gw < NW) {
            const int g = ((b*NC + ch0 + c)*NH + gh)*NW + gw;
            vx = x[g]; vl = l[g]; vu = u[g];
        }
        sP[i] = make_float4(vx, vl, vu, 0.0f);
    }
    __syncthreads();

    const float4* sW4 = (const float4*)sWf;
    float aY = 0.0f, aL = 0.0f, aU = 0.0f;

    #pragma unroll 2
    for (int c = 0; c < CHALF; ++c) {
        const float4 w0 = sW4[(ty*NC + ch0 + c)*3 + 0];
        const float4 w1v = sW4[(ty*NC + ch0 + c)*3 + 1];
        const float4 w2v = sW4[(ty*NC + ch0 + c)*3 + 2];
        const int pb = c*102 + tx;
        tap(w0.x,  sP[pb +  0], aY,aL,aU); tap(w0.y,  sP[pb +  1], aY,aL,aU); tap(w0.z,  sP[pb +  2], aY,aL,aU);
        tap(w1v.x, sP[pb + 34], aY,aL,aU); tap(w1v.y, sP[pb + 35], aY,aL,aU); tap(w1v.z, sP[pb + 36], aY,aL,aU);
        tap(w2v.x, sP[pb + 68], aY,aL,aU); tap(w2v.y, sP[pb + 69], aY,aL,aU); tap(w2v.z, sP[pb + 70], aY,aL,aU);
    }

    const int co = cog*8 + ty;
    const int o  = ((b*NC + co)*NH + h)*NW + tx;
    pY[chalf*PLANE + o] = aY;
    pL[chalf*PLANE + o] = aL;
    pU[chalf*PLANE + o] = aU;
}

// ---- dispatch 2: conv2 + epilogue fused, full 32 channels ------------------
// Block 32(w) x 8(co). Grid (h=32, cog=4, b=4) = 512 blocks. 64 KB LDS.
// Stages s3(p0+p1) of conv1 partials; writes final out = relu(conv + residual).
__global__ __launch_bounds__(256) void conv2epi_k(
    const float* __restrict__ pY, const float* __restrict__ pL, const float* __restrict__ pU,
    const float* __restrict__ x,  const float* __restrict__ l,  const float* __restrict__ u,
    const float* __restrict__ w2,
    float* __restrict__ out)
{
    const int h   = blockIdx.x;
    const int cog = blockIdx.y;
    const int b   = blockIdx.z;
    const int tx  = threadIdx.x;
    const int ty  = threadIdx.y;
    const int tid = ty*32 + tx;

    __shared__ float4 sP[NC*3*34];           // 52224 B
    __shared__ float  sWf[8*NC*3*4];         // 12288 B  -> total 64512 B < 64 KB+pad

    prep_weights_lds(w2, cog, tid, sWf);

    for (int i = tid; i < NC*3*34; i += 256) {
        const int c   = i / 102;
        const int rem = i - c*102;
        const int r   = rem / 34;
        const int col = rem - r*34;
        const int gh  = h + r - 1;
        const int gw  = col - 1;
        float vx = 0.0f, vl = 0.0f, vu = 0.0f;
        if ((unsigned)gh < NH && (unsigned)gw < NW) {
            const int g = ((b*NC + c)*NH + gh)*NW + gw;
            vx = s3(pY[g] + pY[PLANE + g]);  // combine halves + eighth-root (relu no-op)
            vl = s3(pL[g] + pL[PLANE + g]);
            vu = s3(pU[g] + pU[PLANE + g]);
        }
        sP[i] = make_float4(vx, vl, vu, 0.0f);
    }
    __syncthreads();

    const float4* sW4 = (const float4*)sWf;
    float aY = 0.0f, aL = 0.0f, aU = 0.0f;

    #pragma unroll 2
    for (int c = 0; c < NC; ++c) {
        const float4 w0 = sW4[(ty*NC + c)*3 + 0];
        const float4 w1v = sW4[(ty*NC + c)*3 + 1];
        const float4 w2v = sW4[(ty*NC + c)*3 + 2];
        const int pb = c*102 + tx;
        tap(w0.x,  sP[pb +  0], aY,aL,aU); tap(w0.y,  sP[pb +  1], aY,aL,aU); tap(w0.z,  sP[pb +  2], aY,aL,aU);
        tap(w1v.x, sP[pb + 34], aY,aL,aU); tap(w1v.y, sP[pb + 35], aY,aL,aU); tap(w1v.z, sP[pb + 36], aY,aL,aU);
        tap(w2v.x, sP[pb + 68], aY,aL,aU); tap(w2v.y, sP[pb + 69], aY,aL,aU); tap(w2v.z, sP[pb + 70], aY,aL,aU);
    }

    const int co = cog*8 + ty;
    const int o  = ((b*NC + co)*NH + h)*NW + tx;
    out[o]           = fmaxf(s3(aY) + x[o], 0.0f);
    out[PLANE + o]   = fmaxf(s3(aL) + l[o], 0.0f);
    out[2*PLANE + o] = fmaxf(s3(aU) + u[o], 0.0f);
}

extern "C" void kernel_launch(void* const* d_in, const int* in_sizes, int n_in,
                              void* d_out, int out_size, void* d_ws, size_t ws_size,
                              hipStream_t stream)
{
    const float* x  = (const float*)d_in[0];
    const float* l  = (const float*)d_in[1];
    const float* u  = (const float*)d_in[2];
    const float* w1 = (const float*)d_in[3];
    const float* w2 = (const float*)d_in[4];
    float* ws  = (float*)d_ws;
    float* p1Y = ws;                        // conv1 partials: [2][PLANE] each
    float* p1L = p1Y + 2*PLANE;
    float* p1U = p1L + 2*PLANE;
    float* out = (float*)d_out;

    dim3 blk(32, 8);
    conv1_k   <<<dim3(NH, 8, NB), blk, 0, stream>>>(x, l, u, w1, p1Y, p1L, p1U);
    conv2epi_k<<<dim3(NH, 4, NB), blk, 0, stream>>>(p1Y, p1L, p1U, x, l, u, w2, out);
}